// Round 2
// baseline (282.219 us; speedup 1.0000x reference)
//
#include <hip/hip_runtime.h>
#include <hip/hip_fp16.h>

typedef _Float16 half8 __attribute__((ext_vector_type(8)));
typedef float floatx4 __attribute__((ext_vector_type(4)));

#define AS1 __attribute__((address_space(1)))
#define AS3 __attribute__((address_space(3)))

// wperm layout: hi part at [0, 6*512*512), lo part at [WLO_OFF, 2*WLO_OFF)
#define WLO_OFF (6 * 512 * 512)

__device__ __forceinline__ void async_lds16(const void* g, void* l) {
  __builtin_amdgcn_global_load_lds((const AS1 void*)g, (AS3 void*)l, 16, 0, 0);
}

// ---------------------------------------------------------------------------
// P1: convert 6 W matrices [512(k) x 512(n)] fp32 -> fp16 hi + fp16 lo
// (lo = fp16(W - float(hi)), giving ~22-bit effective mantissa), laid out in
// MFMA B-operand fragment order: tile(w, nt, ki) is 4096B; within tile, chunk
// (u, l) at u*1024 + l*16 holds B[k0 + 8*(l>>4) + j][n0 + 16*u + (l&15)],
// j = 0..7 contiguous.
// ---------------------------------------------------------------------------
__global__ __launch_bounds__(256) void permute_w(
    const float* __restrict__ Wir, const float* __restrict__ Whr,
    const float* __restrict__ Wiz, const float* __restrict__ Whz,
    const float* __restrict__ Win, const float* __restrict__ Whn,
    _Float16* __restrict__ wperm) {
  __shared__ __align__(16) float tile[32 * 68];  // padded rows
  const int b = blockIdx.x;
  const int w = b >> 7;         // 0..5
  const int rem = b & 127;
  const int ki = rem >> 3;      // 0..15 (k-tile)
  const int nt = rem & 7;       // 0..7  (n-tile of 64)
  const float* W = (w == 0) ? Wir : (w == 1) ? Whr : (w == 2) ? Wiz
                 : (w == 3) ? Whz : (w == 4) ? Win : Whn;
  const int k0 = ki * 32, n0 = nt * 64;
  const int t = threadIdx.x;

  // coalesced read: thread t reads W[k0 + (t>>3)][n0 + (t&7)*8 .. +7]
  const int kk = t >> 3;
  const int nn = (t & 7) * 8;
  const float* src = W + (k0 + kk) * 512 + n0 + nn;
  float4 f0 = *(const float4*)(src);
  float4 f1 = *(const float4*)(src + 4);
  float* drow = tile + kk * 68 + nn;
  *(float4*)(drow) = f0;
  *(float4*)(drow + 4) = f1;
  __syncthreads();

  // gather fragment chunk c = t: u = t>>6, l = t&63
  const int u = t >> 6, l = t & 63;
  const int nloc = 16 * u + (l & 15);
  const int kbase = 8 * (l >> 4);
  half8 vh, vl;
#pragma unroll
  for (int j = 0; j < 8; ++j) {
    float f = tile[(kbase + j) * 68 + nloc];
    _Float16 hi = (_Float16)f;
    _Float16 lo = (_Float16)(f - (float)hi);
    vh[j] = hi;
    vl[j] = lo;
  }
  const size_t off = ((size_t)((w * 8 + nt) * 16 + ki)) * 2048 + t * 8;
  *(half8*)(wperm + off) = vh;
  *(half8*)(wperm + WLO_OFF + off) = vl;
}

// ---------------------------------------------------------------------------
// Fused GRU with fp16 hi/lo emulated-fp32 MFMA:
//   a*b ~= a_hi*b_hi + a_lo*b_hi + a_hi*b_lo   (residual ~2^-22)
// Block tile 128(m) x 64(n), 4 waves of 64x32, BK=32, K=512.
// W_hi staged to LDS via global_load_lds; W_lo fragments read directly
// global->VGPR (wperm is fragment-ordered, loads are perfectly coalesced).
// 4 acc sets: r, z, in (x-side), hn (h-side). Epilogue fuses the gates.
// ---------------------------------------------------------------------------
__global__ __launch_bounds__(256, 2) void gru_fused(
    const float* __restrict__ x, const float* __restrict__ h,
    const _Float16* __restrict__ wperm,
    const float* __restrict__ br, const float* __restrict__ bz,
    const float* __restrict__ bn, float* __restrict__ out) {
  __shared__ __align__(16) _Float16 ldsXh[128 * 32];  // 8 KB each
  __shared__ __align__(16) _Float16 ldsXl[128 * 32];
  __shared__ __align__(16) _Float16 ldsHh[128 * 32];
  __shared__ __align__(16) _Float16 ldsHl[128 * 32];
  __shared__ __align__(16) _Float16 ldsW[6 * 2048];   // 24 KB (W_hi tiles)

  const int t = threadIdx.x;
  const int lane = t & 63;
  const int wv = t >> 6;
  const int wm = wv >> 1;  // 0..1: wave row block of 64
  const int wn = wv & 1;   // 0..1: wave col block of 32
  const int bid = blockIdx.x;
  const int nt = bid & 7;   // n-tile -> aligns with round-robin XCD for W L2 locality
  const int mt = bid >> 3;
  const int m0 = mt * 128;
  const int n0 = nt * 64;
  const _Float16* wlo = wperm + WLO_OFF;

  floatx4 acc_r[4][2] = {};
  floatx4 acc_z[4][2] = {};
  floatx4 acc_in[4][2] = {};
  floatx4 acc_hn[4][2] = {};

  // x/h staging chunks: c in {t, t+256}; s=c>>6, l=c&63,
  // row m = 16s + (l&15), k offset = 8*(l>>4). Chunk written at base + c*8.
  const int c0 = t, c1 = t + 256;
  const int s0 = c0 >> 6, l0 = c0 & 63;
  const int s1 = c1 >> 6, l1 = c1 & 63;
  const int mA0 = 16 * s0 + (l0 & 15), kA0 = 8 * (l0 >> 4);
  const int mA1 = 16 * s1 + (l1 & 15), kA1 = 8 * (l1 >> 4);

  for (int kt = 0; kt < 16; ++kt) {
    const int k0 = kt * 32;
    __syncthreads();  // previous iter's LDS reads complete before overwrite

    // --- async W_hi tiles: 24 KB = 24 wave-calls of 1 KB; 6 per wave ---
#pragma unroll
    for (int q = 0; q < 6; ++q) {
      const int gg = wv * 6 + q;          // 0..23
      const int w = gg >> 2, u = gg & 3;  // W index, 16-col sub-block
      const char* gsrc = (const char*)wperm +
          ((size_t)((w * 8 + nt) * 16 + kt)) * 4096 + u * 1024 + lane * 16;
      char* ldst = (char*)ldsW + (w * 4 + u) * 1024;
      async_lds16(gsrc, ldst);
    }

    // --- x/h: fp32 load, split hi/lo, fragment-ordered LDS write ---
    {
      const float* px0 = x + (m0 + mA0) * 512 + k0 + kA0;
      const float* px1 = x + (m0 + mA1) * 512 + k0 + kA1;
      const float* ph0 = h + (m0 + mA0) * 512 + k0 + kA0;
      const float* ph1 = h + (m0 + mA1) * 512 + k0 + kA1;
      float v[4][8];
      *(float4*)&v[0][0] = *(const float4*)px0; *(float4*)&v[0][4] = *(const float4*)(px0 + 4);
      *(float4*)&v[1][0] = *(const float4*)px1; *(float4*)&v[1][4] = *(const float4*)(px1 + 4);
      *(float4*)&v[2][0] = *(const float4*)ph0; *(float4*)&v[2][4] = *(const float4*)(ph0 + 4);
      *(float4*)&v[3][0] = *(const float4*)ph1; *(float4*)&v[3][4] = *(const float4*)(ph1 + 4);
      half8 hi[4], lo[4];
#pragma unroll
      for (int g = 0; g < 4; ++g) {
#pragma unroll
        for (int j = 0; j < 8; ++j) {
          _Float16 a = (_Float16)v[g][j];
          hi[g][j] = a;
          lo[g][j] = (_Float16)(v[g][j] - (float)a);
        }
      }
      *(half8*)(ldsXh + c0 * 8) = hi[0]; *(half8*)(ldsXl + c0 * 8) = lo[0];
      *(half8*)(ldsXh + c1 * 8) = hi[1]; *(half8*)(ldsXl + c1 * 8) = lo[1];
      *(half8*)(ldsHh + c0 * 8) = hi[2]; *(half8*)(ldsHl + c0 * 8) = lo[2];
      *(half8*)(ldsHh + c1 * 8) = hi[3]; *(half8*)(ldsHl + c1 * 8) = lo[3];
    }
    __syncthreads();  // drains vmcnt (global_load_lds) + lgkmcnt

    // --- compute: 144 MFMA / wave / k-step ---
    half8 axh[4], ahh[4];
#pragma unroll
    for (int i = 0; i < 4; ++i) {
      axh[i] = *(const half8*)(ldsXh + ((wm * 4 + i) * 64 + lane) * 8);
      ahh[i] = *(const half8*)(ldsHh + ((wm * 4 + i) * 64 + lane) * 8);
    }
#pragma unroll
    for (int jn = 0; jn < 2; ++jn) {
      const int bo = (wn * 2 + jn) * 512 + lane * 8;
      // W_lo fragments direct from global (prefetchable, coalesced 16B/lane)
      const size_t tb = ((size_t)(nt * 16 + kt)) * 2048 + bo;
      half8 bl_ir = *(const half8*)(wlo + tb + (size_t)0 * 8 * 16 * 2048);
      half8 bl_hr = *(const half8*)(wlo + tb + (size_t)1 * 8 * 16 * 2048);
      half8 bl_iz = *(const half8*)(wlo + tb + (size_t)2 * 8 * 16 * 2048);
      half8 bl_hz = *(const half8*)(wlo + tb + (size_t)3 * 8 * 16 * 2048);
      half8 bl_in = *(const half8*)(wlo + tb + (size_t)4 * 8 * 16 * 2048);
      half8 bl_hn = *(const half8*)(wlo + tb + (size_t)5 * 8 * 16 * 2048);
      // W_hi fragments from LDS
      half8 bh_ir = *(const half8*)(ldsW + 0 * 2048 + bo);
      half8 bh_hr = *(const half8*)(ldsW + 1 * 2048 + bo);
      half8 bh_iz = *(const half8*)(ldsW + 2 * 2048 + bo);
      half8 bh_hz = *(const half8*)(ldsW + 3 * 2048 + bo);
      half8 bh_in = *(const half8*)(ldsW + 4 * 2048 + bo);
      half8 bh_hn = *(const half8*)(ldsW + 5 * 2048 + bo);
      // phase 1: B_hi x (A_hi + A_lo)
#pragma unroll
      for (int i = 0; i < 4; ++i) {
        half8 axl = *(const half8*)(ldsXl + ((wm * 4 + i) * 64 + lane) * 8);
        half8 ahl = *(const half8*)(ldsHl + ((wm * 4 + i) * 64 + lane) * 8);
        acc_r[i][jn]  = __builtin_amdgcn_mfma_f32_16x16x32_f16(axh[i], bh_ir, acc_r[i][jn], 0, 0, 0);
        acc_r[i][jn]  = __builtin_amdgcn_mfma_f32_16x16x32_f16(axl,    bh_ir, acc_r[i][jn], 0, 0, 0);
        acc_r[i][jn]  = __builtin_amdgcn_mfma_f32_16x16x32_f16(ahh[i], bh_hr, acc_r[i][jn], 0, 0, 0);
        acc_r[i][jn]  = __builtin_amdgcn_mfma_f32_16x16x32_f16(ahl,    bh_hr, acc_r[i][jn], 0, 0, 0);
        acc_z[i][jn]  = __builtin_amdgcn_mfma_f32_16x16x32_f16(axh[i], bh_iz, acc_z[i][jn], 0, 0, 0);
        acc_z[i][jn]  = __builtin_amdgcn_mfma_f32_16x16x32_f16(axl,    bh_iz, acc_z[i][jn], 0, 0, 0);
        acc_z[i][jn]  = __builtin_amdgcn_mfma_f32_16x16x32_f16(ahh[i], bh_hz, acc_z[i][jn], 0, 0, 0);
        acc_z[i][jn]  = __builtin_amdgcn_mfma_f32_16x16x32_f16(ahl,    bh_hz, acc_z[i][jn], 0, 0, 0);
        acc_in[i][jn] = __builtin_amdgcn_mfma_f32_16x16x32_f16(axh[i], bh_in, acc_in[i][jn], 0, 0, 0);
        acc_in[i][jn] = __builtin_amdgcn_mfma_f32_16x16x32_f16(axl,    bh_in, acc_in[i][jn], 0, 0, 0);
        acc_hn[i][jn] = __builtin_amdgcn_mfma_f32_16x16x32_f16(ahh[i], bh_hn, acc_hn[i][jn], 0, 0, 0);
        acc_hn[i][jn] = __builtin_amdgcn_mfma_f32_16x16x32_f16(ahl,    bh_hn, acc_hn[i][jn], 0, 0, 0);
      }
      // phase 2: A_hi x B_lo
#pragma unroll
      for (int i = 0; i < 4; ++i) {
        acc_r[i][jn]  = __builtin_amdgcn_mfma_f32_16x16x32_f16(axh[i], bl_ir, acc_r[i][jn], 0, 0, 0);
        acc_r[i][jn]  = __builtin_amdgcn_mfma_f32_16x16x32_f16(ahh[i], bl_hr, acc_r[i][jn], 0, 0, 0);
        acc_z[i][jn]  = __builtin_amdgcn_mfma_f32_16x16x32_f16(axh[i], bl_iz, acc_z[i][jn], 0, 0, 0);
        acc_z[i][jn]  = __builtin_amdgcn_mfma_f32_16x16x32_f16(ahh[i], bl_hz, acc_z[i][jn], 0, 0, 0);
        acc_in[i][jn] = __builtin_amdgcn_mfma_f32_16x16x32_f16(axh[i], bl_in, acc_in[i][jn], 0, 0, 0);
        acc_hn[i][jn] = __builtin_amdgcn_mfma_f32_16x16x32_f16(ahh[i], bl_hn, acc_hn[i][jn], 0, 0, 0);
      }
    }
  }

  // --- epilogue: gates + h_new. C/D layout: col = lane&15, row = quad*4+reg ---
  const int quad = lane >> 4;
  const int col = lane & 15;
#pragma unroll
  for (int i = 0; i < 4; ++i) {
    const int mbase = m0 + wm * 64 + i * 16 + quad * 4;
#pragma unroll
    for (int jn = 0; jn < 2; ++jn) {
      const int n = n0 + wn * 32 + jn * 16 + col;
      const float vbr = br[n], vbz = bz[n], vbn = bn[n];
#pragma unroll
      for (int r = 0; r < 4; ++r) {
        const int m = mbase + r;
        const float gr = acc_r[i][jn][r] + vbr;
        const float gz = acc_z[i][jn][r] + vbz;
        const float rg = 1.0f / (1.0f + __expf(-gr));
        const float zg = 1.0f / (1.0f + __expf(-gz));
        const float gn = acc_in[i][jn][r] + rg * acc_hn[i][jn][r] + vbn;
        const float e2 = __expf(2.0f * gn);          // inf-safe: tanh->+/-1
        const float ntv = 1.0f - 2.0f / (e2 + 1.0f);
        const float hp = h[m * 512 + n];
        out[m * 512 + n] = (1.0f - zg) * ntv + zg * hp;
      }
    }
  }
}

extern "C" void kernel_launch(void* const* d_in, const int* in_sizes, int n_in,
                              void* d_out, int out_size, void* d_ws, size_t ws_size,
                              hipStream_t stream) {
  const float* x   = (const float*)d_in[0];
  const float* h   = (const float*)d_in[1];
  const float* Wir = (const float*)d_in[2];
  const float* Whr = (const float*)d_in[3];
  const float* br  = (const float*)d_in[4];
  const float* Wiz = (const float*)d_in[5];
  const float* Whz = (const float*)d_in[6];
  const float* bz  = (const float*)d_in[7];
  const float* Win = (const float*)d_in[8];
  const float* Whn = (const float*)d_in[9];
  const float* bn  = (const float*)d_in[10];
  float* out = (float*)d_out;
  _Float16* wperm = (_Float16*)d_ws;  // needs 2 * 6*512*512*2 = 6.3 MB

  permute_w<<<768, 256, 0, stream>>>(Wir, Whr, Wiz, Whz, Win, Whn, wperm);
  gru_fused<<<1024, 256, 0, stream>>>(x, h, wperm, br, bz, bn, out);
}